// Round 1
// baseline (25.479 us; speedup 1.0000x reference)
//
#include <hip/hip_runtime.h>

#define VOCAB 1024
#define ARCS  16
#define MAX_ORDER 4
#define START_STATE 0
#define BLOCK 256
#define CHAIN (MAX_ORDER - 1)

__global__ __launch_bounds__(BLOCK) void ngram_advance_kernel(
    const float* __restrict__ arcs_weights,
    const float* __restrict__ backoff_weights,
    const int*   __restrict__ ilabels,
    const int*   __restrict__ to_states,
    const int*   __restrict__ backoff_to,
    const int*   __restrict__ state_start,
    const int*   __restrict__ state_end,
    const int*   __restrict__ states,
    float*       __restrict__ out_scores,   // [B, V]
    float*       __restrict__ out_next)     // [B, V] next-state ids as f32
{
    __shared__ float s_scores[VOCAB];
    __shared__ float s_next[VOCAB];
    __shared__ int   s_chain_state[CHAIN];
    __shared__ float s_chain_acc[CHAIN];
    __shared__ float s_acc_final;

    const int b   = blockIdx.x;
    const int tid = threadIdx.x;

    // Phase 1: walk the backoff chain (dependent loads, single thread).
    if (tid == 0) {
        int   cur = states[b];
        float acc = 0.0f;
        #pragma unroll
        for (int t = 0; t < CHAIN; ++t) {
            s_chain_state[t] = cur;
            s_chain_acc[t]   = acc;   // acc BEFORE this state's backoff weight
            if (cur != START_STATE) {
                acc += backoff_weights[cur];
                cur  = backoff_to[cur];
            }
        }
        s_acc_final = acc;
    }
    __syncthreads();

    // Phase 2: dense fill with the start state's arc table (arc index == label).
    const float accf = s_acc_final;
    #pragma unroll
    for (int i = 0; i < VOCAB / BLOCK; ++i) {
        const int v = tid + i * BLOCK;
        s_scores[v] = accf + arcs_weights[v];
        s_next[v]   = (float)to_states[v];
    }
    __syncthreads();

    // Phase 3: overlay chain arcs, t = CHAIN-1 .. 0 so that the
    // highest-order (t=0) state's arcs win — matches first-write-wins
    // (found_e) semantics of the reference. Single wave => LDS ops are
    // program-ordered, no barrier needed between t-levels.
    if (tid < ARCS) {
        #pragma unroll
        for (int t = CHAIN - 1; t >= 0; --t) {
            const int s = s_chain_state[t];
            if (s != START_STATE) {
                const int idx = state_start[s] + tid;
                if (idx < state_end[s]) {
                    const int lab = ilabels[idx];
                    s_scores[lab] = s_chain_acc[t] + arcs_weights[idx];
                    s_next[lab]   = (float)to_states[idx];
                }
            }
        }
    }
    __syncthreads();

    // Phase 4: coalesced store.
    float* __restrict__ so = out_scores + (size_t)b * VOCAB;
    float* __restrict__ no = out_next   + (size_t)b * VOCAB;
    #pragma unroll
    for (int i = 0; i < VOCAB / BLOCK; ++i) {
        const int v = tid + i * BLOCK;
        so[v] = s_scores[v];
        no[v] = s_next[v];
    }
}

extern "C" void kernel_launch(void* const* d_in, const int* in_sizes, int n_in,
                              void* d_out, int out_size, void* d_ws, size_t ws_size,
                              hipStream_t stream) {
    const float* arcs_weights    = (const float*)d_in[0];
    const float* backoff_weights = (const float*)d_in[1];
    const int*   ilabels         = (const int*)d_in[2];
    const int*   to_states       = (const int*)d_in[3];
    const int*   backoff_to      = (const int*)d_in[4];
    const int*   state_start     = (const int*)d_in[5];
    const int*   state_end       = (const int*)d_in[6];
    const int*   states          = (const int*)d_in[7];

    const int B = in_sizes[7];                 // 8192 hypotheses
    float* out_scores = (float*)d_out;         // first B*V floats
    float* out_next   = out_scores + (size_t)B * VOCAB;  // second B*V

    ngram_advance_kernel<<<B, BLOCK, 0, stream>>>(
        arcs_weights, backoff_weights, ilabels, to_states, backoff_to,
        state_start, state_end, states, out_scores, out_next);
}

// Round 2
// 19.359 us; speedup vs baseline: 1.3161x; 1.3161x over previous
//
#include <hip/hip_runtime.h>

#define VOCAB 1024
#define ARCS  16
#define MAX_ORDER 4
#define CHAIN (MAX_ORDER - 1)
#define START_STATE 0
#define WAVE 64

// One wave (64 threads) per hypothesis.
// LDS holds only the sparse overlay (sentinel next == -1 means "no overlay");
// dense start-state defaults stay in registers (tables are L1/L2-hot).
__global__ __launch_bounds__(WAVE) void ngram_advance_kernel(
    const float* __restrict__ arcs_weights,
    const float* __restrict__ backoff_weights,
    const int*   __restrict__ ilabels,
    const int*   __restrict__ to_states,
    const int*   __restrict__ backoff_to,
    const int*   __restrict__ state_start,
    const int*   __restrict__ state_end,
    const int*   __restrict__ states,
    float*       __restrict__ out_scores,   // [B, V]
    float*       __restrict__ out_next)     // [B, V] state ids as f32
{
    __shared__ int   s_next_ov[VOCAB];   // -1 = not found
    __shared__ float s_score_ov[VOCAB];

    const int tid = threadIdx.x;
    const int b   = blockIdx.x;

    // ---- Phase A: sentinel init (4 x ds_write_b128) ----
    #pragma unroll
    for (int i = 0; i < VOCAB / (WAVE * 4); ++i) {
        const int v = (tid + i * WAVE) * 4;
        *(int4*)&s_next_ov[v] = make_int4(-1, -1, -1, -1);
    }

    // ---- Phase B: chain walk, uniform across all lanes (registers only).
    // Same address per hop for all 64 lanes -> one cache line, HW broadcast.
    int   cs[CHAIN];
    float ca[CHAIN];
    int   cur = states[b];
    float acc = 0.0f;
    #pragma unroll
    for (int t = 0; t < CHAIN; ++t) {
        cs[t] = cur;
        ca[t] = acc;                    // acc BEFORE this state's backoff wt
        if (cur != START_STATE) {
            acc += backoff_weights[cur];
            cur  = backoff_to[cur];
        }
    }
    const float accf = acc;

    // ---- Phase C: parallel arc fetch, lanes 0..47: level = tid>>4, arc = tid&15
    const int level = tid >> 4;
    const int arc   = tid & (ARCS - 1);
    bool  ok  = false;
    int   lab = 0, ns = 0;
    float sc  = 0.0f;
    if (tid < CHAIN * ARCS) {
        const int s = (level == 0) ? cs[0] : ((level == 1) ? cs[1] : cs[2]);
        if (s != START_STATE) {
            const int st  = state_start[s];
            const int en  = state_end[s];
            const int idx = st + arc;
            if (idx < en) {
                ok  = true;
                lab = ilabels[idx];
                sc  = ((level == 0) ? ca[0] : ((level == 1) ? ca[1] : ca[2]))
                      + arcs_weights[idx];
                ns  = to_states[idx];
            }
        }
    }
    __syncthreads();   // init complete (cheap: single wave)

    // ---- Ordered commits: level 2, then 1, then 0 (level 0 wins = highest
    // order state = reference's first-write-wins). Barriers between groups
    // prevent the compiler from merging the predicated same-register stores
    // into one instruction (cross-lane same-address conflict would lose the
    // priority order).
    if (ok && level == 2) { s_score_ov[lab] = sc; s_next_ov[lab] = ns; }
    __syncthreads();
    if (ok && level == 1) { s_score_ov[lab] = sc; s_next_ov[lab] = ns; }
    __syncthreads();
    if (ok && level == 0) { s_score_ov[lab] = sc; s_next_ov[lab] = ns; }
    __syncthreads();

    // ---- Phase E: dense default + overlay select + coalesced float4 stores
    float* __restrict__ so = out_scores + (size_t)b * VOCAB;
    float* __restrict__ no = out_next   + (size_t)b * VOCAB;
    #pragma unroll
    for (int i = 0; i < VOCAB / (WAVE * 4); ++i) {
        const int v = (tid + i * WAVE) * 4;
        const int4   ons = *(const int4*)  &s_next_ov[v];
        const float4 osc = *(const float4*)&s_score_ov[v];
        const float4 dw  = *(const float4*)&arcs_weights[v];  // dense table (hot)
        const int4   dn  = *(const int4*)  &to_states[v];     // dense table (hot)
        float4 rs, rn;
        rs.x = (ons.x >= 0) ? osc.x : accf + dw.x;
        rs.y = (ons.y >= 0) ? osc.y : accf + dw.y;
        rs.z = (ons.z >= 0) ? osc.z : accf + dw.z;
        rs.w = (ons.w >= 0) ? osc.w : accf + dw.w;
        rn.x = (float)((ons.x >= 0) ? ons.x : dn.x);
        rn.y = (float)((ons.y >= 0) ? ons.y : dn.y);
        rn.z = (float)((ons.z >= 0) ? ons.z : dn.z);
        rn.w = (float)((ons.w >= 0) ? ons.w : dn.w);
        *(float4*)&so[v] = rs;
        *(float4*)&no[v] = rn;
    }
}

extern "C" void kernel_launch(void* const* d_in, const int* in_sizes, int n_in,
                              void* d_out, int out_size, void* d_ws, size_t ws_size,
                              hipStream_t stream) {
    const float* arcs_weights    = (const float*)d_in[0];
    const float* backoff_weights = (const float*)d_in[1];
    const int*   ilabels         = (const int*)d_in[2];
    const int*   to_states       = (const int*)d_in[3];
    const int*   backoff_to      = (const int*)d_in[4];
    const int*   state_start     = (const int*)d_in[5];
    const int*   state_end       = (const int*)d_in[6];
    const int*   states          = (const int*)d_in[7];

    const int B = in_sizes[7];                           // 8192 hypotheses
    float* out_scores = (float*)d_out;                   // first B*V floats
    float* out_next   = out_scores + (size_t)B * VOCAB;  // second B*V

    ngram_advance_kernel<<<B, WAVE, 0, stream>>>(
        arcs_weights, backoff_weights, ilabels, to_states, backoff_to,
        state_start, state_end, states, out_scores, out_next);
}